// Round 4
// baseline (974.637 us; speedup 1.0000x reference)
//
#include <hip/hip_runtime.h>
#include <hip/hip_cooperative_groups.h>

namespace cg = cooperative_groups;

#define BB 16
#define LL 2048
#define HH 1024
#define ZZ 512
#define NEGV -1e9f
#define GRID 1024

__device__ __forceinline__ float dot4(float4 a, float4 b) {
    return a.x * b.x + a.y * b.y + a.z * b.z + a.w * b.w;
}

// Single cooperative kernel; phases separated by grid.sync().
// ws layout (floats): zsum[8192] kbuf[16384] Vs[8192]  (these 32768 pre-zeroed)
//                     sbuf[32768] wbuf[32768] kq[16384]
__global__ __launch_bounds__(256, 4) void k_fused(
    const float* __restrict__ erhs, const float* __restrict__ efhs,
    const float* __restrict__ zseq, const int* __restrict__ mask,
    const float* __restrict__ Wq, const float* __restrict__ Wk,
    const float* __restrict__ Wv, float* __restrict__ out,
    float* __restrict__ attn, float* __restrict__ ws)
{
    float* zsum = ws;             //  8192
    float* kbuf = ws + 8192;      // 16384
    float* Vs   = ws + 24576;     //  8192
    float* sbuf = ws + 32768;     // 32768
    float* wbuf = ws + 65536;     // 32768
    float* kq   = ws + 98304;     // 16384

    cg::grid_group grid = cg::this_grid();
    const int beta = blockIdx.x;
    const int t    = threadIdx.x;
    const int wid  = t >> 6, lane = t & 63;

    __shared__ float es[LL];
    __shared__ float red[16];

    // ---------- P1: kbuf partials (blocks 0..63) + zsum (blocks 64..575) ----------
    if (beta < 64) {
        // kbuf[b,hp] += sum over h-segment of efhs[b,h]*Wk[h,hp]
        int b = beta >> 2, hseg = beta & 3;          // h in [hseg*256, hseg*256+256)
        const float* e  = efhs + b * HH + hseg * 256;
        const float* wk = Wk + (size_t)(hseg * 256) * HH;
        float a0 = 0.f, a1 = 0.f, a2 = 0.f, a3 = 0.f;
        for (int h = 0; h < 256; ++h) {
            float ev = e[h];
            const float* wr = wk + (size_t)h * HH;
            a0 += ev * wr[t];
            a1 += ev * wr[t + 256];
            a2 += ev * wr[t + 512];
            a3 += ev * wr[t + 768];
        }
        atomicAdd(&kbuf[b * HH + t],       a0);
        atomicAdd(&kbuf[b * HH + t + 256], a1);
        atomicAdd(&kbuf[b * HH + t + 512], a2);
        atomicAdd(&kbuf[b * HH + t + 768], a3);
    } else if (beta < 576) {
        // zsum[b,z0] += 64-row chunk of zseq
        int blk = beta - 64;                          // b(16) x jc(32)
        int b = blk >> 5, jc = blk & 31;
        const float* p = zseq + ((size_t)(b * LL + jc * 64)) * ZZ;
        float a0 = 0.f, a1 = 0.f;
        for (int j = 0; j < 64; ++j) {
            const float* pj = p + (size_t)j * ZZ;
            a0 += pj[t];
            a1 += pj[t + 256];
        }
        atomicAdd(&zsum[b * ZZ + t],       a0);
        atomicAdd(&zsum[b * ZZ + t + 256], a1);
    }
    grid.sync();

    // ---------- P2: kq (blocks 0..255) + Vs (blocks 256..383) ----------
    if (beta < 256) {
        // wave per h-row: kq[b,h] = Wq[h,:].kbuf[b,:] for all 16 b
        int h = beta * 4 + wid;
        const float4* wrow = (const float4*)(Wq + (size_t)h * HH);
        float4 w0 = wrow[lane], w1 = wrow[64 + lane],
               w2 = wrow[128 + lane], w3 = wrow[192 + lane];
        for (int b = 0; b < BB; ++b) {
            const float4* kb = (const float4*)(kbuf + b * HH);
            float acc = dot4(w0, kb[lane]) + dot4(w1, kb[64 + lane])
                      + dot4(w2, kb[128 + lane]) + dot4(w3, kb[192 + lane]);
            for (int off = 32; off > 0; off >>= 1) acc += __shfl_down(acc, off);
            if (lane == 0) kq[b * HH + h] = acc;
        }
    } else if (beta < 384) {
        // Vs[b,z] += (z0-chunk) zsum[b,z0]*Wv[z0,z]
        int blk = beta - 256;                         // b(16) x z0c(8)
        int b = blk >> 3, z0c = blk & 7;
        const float* zs = zsum + b * ZZ + z0c * 64;
        const float* wv = Wv + (size_t)(z0c * 64) * ZZ;
        float a0 = 0.f, a1 = 0.f;
        for (int z0 = 0; z0 < 64; ++z0) {
            float zv = zs[z0];
            const float* wr = wv + (size_t)z0 * ZZ;
            a0 += zv * wr[t];
            a1 += zv * wr[t + 256];
        }
        atomicAdd(&Vs[b * ZZ + t],       a0);
        atomicAdd(&Vs[b * ZZ + t + 256], a1);
    }
    grid.sync();

    // ---------- P3: scores (all blocks; wave per row, 8 rows/wave) ----------
    {
        int gw = beta * 4 + wid;                      // 4096 waves
        int row0 = gw * 8;
        int b = row0 >> 11;                           // 8 rows share b
        const float4* kb = (const float4*)(kq + b * HH);
        float4 k0 = kb[lane], k1 = kb[64 + lane],
               k2 = kb[128 + lane], k3 = kb[192 + lane];
        for (int r = 0; r < 8; ++r) {
            int row = row0 + r;
            const float4* e = (const float4*)(erhs + (size_t)row * HH);
            float acc = dot4(e[lane], k0) + dot4(e[64 + lane], k1)
                      + dot4(e[128 + lane], k2) + dot4(e[192 + lane], k3);
            for (int off = 32; off > 0; off >>= 1) acc += __shfl_down(acc, off);
            if (lane == 0) {
                float v = acc * (1.0f / 32.0f);
                if (mask[row] == 0) v = NEGV;
                sbuf[row] = v;
            }
        }
    }
    grid.sync();

    // ---------- P4: softmax over i (blocks 0..15) ----------
    if (beta < 16) {
        int b = beta;
        const float* sb = sbuf + b * LL;
        float m = -3.4e38f;
        for (int i = t; i < LL; i += 256) m = fmaxf(m, sb[i]);
        for (int off = 32; off > 0; off >>= 1) m = fmaxf(m, __shfl_down(m, off));
        if (lane == 0) red[wid] = m;
        __syncthreads();
        if (t == 0) {
            float mm = red[0];
            for (int i = 1; i < 4; ++i) mm = fmaxf(mm, red[i]);
            red[0] = mm;
        }
        __syncthreads();
        m = red[0];
        float ssum = 0.f;
        for (int i = t; i < LL; i += 256) {
            float e = __expf(sb[i] - m);
            es[i] = e;
            ssum += e;
        }
        for (int off = 32; off > 0; off >>= 1) ssum += __shfl_down(ssum, off);
        if (lane == 0) red[8 + wid] = ssum;
        __syncthreads();
        if (t == 0) {
            float tt = 0.f;
            for (int i = 0; i < 4; ++i) tt += red[8 + i];
            red[8] = tt;
        }
        __syncthreads();
        float inv = 1.0f / red[8];
        for (int i = t; i < LL; i += 256) wbuf[b * LL + i] = es[i] * inv;
    }
    grid.sync();

    // ---------- P5: out + attn (all blocks; 32 rows/block) ----------
    {
        int row0 = beta * 32;
        for (int r = 0; r < 32; ++r) {
            int row = row0 + r;
            int b = row >> 11;
            float wvv = wbuf[row];
            if (t < 128) {
                float4 v = ((const float4*)(Vs + b * ZZ))[t];
                ((float4*)(out + (size_t)row * ZZ))[t] =
                    make_float4(wvv * v.x, wvv * v.y, wvv * v.z, wvv * v.w);
            }
            float4 pk = make_float4(wvv, wvv, wvv, wvv);
            float4* p = (float4*)attn + (size_t)row * 512;
            p[t]       = pk;
            p[t + 256] = pk;
        }
    }
}

extern "C" void kernel_launch(void* const* d_in, const int* in_sizes, int n_in,
                              void* d_out, int out_size, void* d_ws, size_t ws_size,
                              hipStream_t stream) {
    const float* erhs = (const float*)d_in[0];  // [B,L,H]
    const float* efhs = (const float*)d_in[1];  // [B,H]
    const float* zseq = (const float*)d_in[2];  // [B,L,Z]
    const int*   mask = (const int*)d_in[3];    // [B,L]
    const float* Wq   = (const float*)d_in[4];  // [H,H]
    const float* Wk   = (const float*)d_in[5];  // [H,H]
    const float* Wv   = (const float*)d_in[6];  // [Z,Z]
    float* out  = (float*)d_out;
    float* attn = out + (size_t)BB * LL * ZZ;
    float* ws   = (float*)d_ws;

    // zero the atomic-accumulated buffers (zsum+kbuf+Vs = first 32768 floats)
    hipMemsetAsync(ws, 0, 32768 * sizeof(float), stream);

    void* args[] = {
        (void*)&erhs, (void*)&efhs, (void*)&zseq, (void*)&mask,
        (void*)&Wq, (void*)&Wk, (void*)&Wv,
        (void*)&out, (void*)&attn, (void*)&ws,
    };
    hipLaunchCooperativeKernel((const void*)k_fused, dim3(GRID), dim3(256),
                               args, 0, stream);
}

// Round 5
// 504.776 us; speedup vs baseline: 1.9308x; 1.9308x over previous
//
#include <hip/hip_runtime.h>

#define BB 16
#define LL 2048
#define HH 1024
#define ZZ 512
#define NEGV -1e9f

typedef float v4f __attribute__((ext_vector_type(4)));

__device__ __forceinline__ float dot4(float4 a, float4 b) {
    return a.x * b.x + a.y * b.y + a.z * b.z + a.w * b.w;
}

// Dispatch A: blocks [0,128): kbuf[b,hp] += sum over 128-h segment of efhs[b,h]*Wk[h,hp]
//             blocks [128,640): zsum[b,z0] += 64-row chunk of zseq[b,:,z0]
__global__ __launch_bounds__(256) void kA(const float* __restrict__ efhs,
                                          const float* __restrict__ Wk,
                                          const float* __restrict__ zseq,
                                          float* __restrict__ kbuf,
                                          float* __restrict__ zsum) {
    int t = threadIdx.x;
    if (blockIdx.x < 128) {
        int b = blockIdx.x >> 3, hseg = blockIdx.x & 7;   // h in [hseg*128, +128)
        const float* e  = efhs + b * HH + hseg * 128;
        const float* wk = Wk + (size_t)(hseg * 128) * HH;
        float a0 = 0.f, a1 = 0.f, a2 = 0.f, a3 = 0.f;
        for (int h = 0; h < 128; ++h) {
            float ev = e[h];
            const float* wr = wk + (size_t)h * HH;
            a0 += ev * wr[t];
            a1 += ev * wr[t + 256];
            a2 += ev * wr[t + 512];
            a3 += ev * wr[t + 768];
        }
        atomicAdd(&kbuf[b * HH + t],       a0);
        atomicAdd(&kbuf[b * HH + t + 256], a1);
        atomicAdd(&kbuf[b * HH + t + 512], a2);
        atomicAdd(&kbuf[b * HH + t + 768], a3);
    } else {
        int blk = blockIdx.x - 128;                        // b(16) x jc(32)
        int b = blk >> 5, jc = blk & 31;
        const float* p = zseq + ((size_t)(b * LL + jc * 64)) * ZZ;
        float a0 = 0.f, a1 = 0.f;
        for (int j = 0; j < 64; ++j) {
            const float* pj = p + (size_t)j * ZZ;
            a0 += pj[t];
            a1 += pj[t + 256];
        }
        atomicAdd(&zsum[b * ZZ + t],       a0);
        atomicAdd(&zsum[b * ZZ + t + 256], a1);
    }
}

// Dispatch B: blocks [0,4096): kq[b,h] = Wq[h,:].kbuf[b,:]  (wave per (h,b) pair)
//             blocks [4096,4224): Vs[b,z] += (z0-chunk) zsum[b,z0]*Wv[z0,z]
__global__ __launch_bounds__(256) void kB(const float* __restrict__ Wq,
                                          const float* __restrict__ kbuf,
                                          const float* __restrict__ zsum,
                                          const float* __restrict__ Wv,
                                          float* __restrict__ kq,
                                          float* __restrict__ Vs) {
    int t = threadIdx.x;
    int wid = t >> 6, lane = t & 63;
    if (blockIdx.x < 4096) {
        int h = blockIdx.x >> 2;
        int b = ((blockIdx.x & 3) << 2) + wid;
        const float4* wrow = (const float4*)(Wq + (size_t)h * HH);
        const float4* kb   = (const float4*)(kbuf + b * HH);
        float acc = dot4(wrow[lane], kb[lane])
                  + dot4(wrow[64 + lane], kb[64 + lane])
                  + dot4(wrow[128 + lane], kb[128 + lane])
                  + dot4(wrow[192 + lane], kb[192 + lane]);
        for (int off = 32; off > 0; off >>= 1) acc += __shfl_down(acc, off);
        if (lane == 0) kq[b * HH + h] = acc;
    } else {
        int blk = blockIdx.x - 4096;                       // b(16) x z0c(8)
        int b = blk >> 3, z0c = blk & 7;
        const float* zs = zsum + b * ZZ + z0c * 64;
        const float* wv = Wv + (size_t)(z0c * 64) * ZZ;
        float a0 = 0.f, a1 = 0.f;
        for (int z0 = 0; z0 < 64; ++z0) {
            float zv = zs[z0];
            const float* wr = wv + (size_t)z0 * ZZ;
            a0 += zv * wr[t];
            a1 += zv * wr[t + 256];
        }
        atomicAdd(&Vs[b * ZZ + t],       a0);
        atomicAdd(&Vs[b * ZZ + t + 256], a1);
    }
}

// Dispatch C: s[b,i] = (erhs[b,i].kq[b])/32, masked  (wave per row; pure erhs stream)
__global__ __launch_bounds__(256) void kC(const float* __restrict__ erhs,
                                          const float* __restrict__ kq,
                                          const int* __restrict__ mask,
                                          float* __restrict__ sbuf) {
    int row = blockIdx.x * 4 + (threadIdx.x >> 6);  // b*L + i
    int lane = threadIdx.x & 63;
    int b = row >> 11;
    const float4* e  = (const float4*)(erhs + (size_t)row * HH);
    const float4* kb = (const float4*)(kq + b * HH);
    float acc = dot4(e[lane], kb[lane])
              + dot4(e[64 + lane], kb[64 + lane])
              + dot4(e[128 + lane], kb[128 + lane])
              + dot4(e[192 + lane], kb[192 + lane]);
    for (int off = 32; off > 0; off >>= 1) acc += __shfl_down(acc, off);
    if (lane == 0) {
        float v = acc * (1.0f / 32.0f);
        if (mask[row] == 0) v = NEGV;
        sbuf[row] = v;
    }
}

// Dispatch D: w[b,:] = softmax_i(s[b,:])  (one block per b; sbuf is L2-hot)
__global__ __launch_bounds__(256) void kD(const float* __restrict__ sbuf,
                                          float* __restrict__ wbuf) {
    __shared__ float es[LL];
    __shared__ float red[16];
    int b = blockIdx.x, t = threadIdx.x;
    int wid = t >> 6, lane = t & 63;
    const float* sb = sbuf + b * LL;
    float m = -3.4e38f;
    for (int i = t; i < LL; i += 256) m = fmaxf(m, sb[i]);
    for (int off = 32; off > 0; off >>= 1) m = fmaxf(m, __shfl_down(m, off));
    if (lane == 0) red[wid] = m;
    __syncthreads();
    if (t == 0) {
        float mm = red[0];
        for (int i = 1; i < 4; ++i) mm = fmaxf(mm, red[i]);
        red[0] = mm;
    }
    __syncthreads();
    m = red[0];
    float ssum = 0.f;
    for (int i = t; i < LL; i += 256) {
        float e = __expf(sb[i] - m);
        es[i] = e;
        ssum += e;
    }
    for (int off = 32; off > 0; off >>= 1) ssum += __shfl_down(ssum, off);
    if (lane == 0) red[8 + wid] = ssum;
    __syncthreads();
    if (t == 0) {
        float tt = 0.f;
        for (int i = 0; i < 4; ++i) tt += red[8 + i];
        red[8] = tt;
    }
    __syncthreads();
    float inv = 1.0f / red[8];
    for (int i = t; i < LL; i += 256) wbuf[b * LL + i] = es[i] * inv;
}

// Dispatch E: 8 rows per block; Vs register-cached; non-temporal float4 stores.
//   out[b,i,:]  = w[b,i]*Vs[b,:]   attn[b,i,:] = w[b,i]
__global__ __launch_bounds__(256) void kE(const float* __restrict__ wbuf,
                                          const float* __restrict__ Vs,
                                          float* __restrict__ out,
                                          float* __restrict__ attn) {
    int row0 = blockIdx.x * 8;      // all 8 rows share b (256 blocks per b)
    int b = row0 >> 11;
    int t = threadIdx.x;
    float4 v = make_float4(0.f, 0.f, 0.f, 0.f);
    if (t < 128) v = ((const float4*)(Vs + b * ZZ))[t];
#pragma unroll
    for (int r = 0; r < 8; ++r) {
        int row = row0 + r;
        float wv = wbuf[row];
        if (t < 128) {
            v4f ov = {wv * v.x, wv * v.y, wv * v.z, wv * v.w};
            __builtin_nontemporal_store(ov, (v4f*)(out + (size_t)row * ZZ) + t);
        }
        v4f pk = {wv, wv, wv, wv};
        v4f* p = (v4f*)(attn + (size_t)row * LL);
        __builtin_nontemporal_store(pk, p + t);
        __builtin_nontemporal_store(pk, p + t + 256);
    }
}

extern "C" void kernel_launch(void* const* d_in, const int* in_sizes, int n_in,
                              void* d_out, int out_size, void* d_ws, size_t ws_size,
                              hipStream_t stream) {
    const float* erhs = (const float*)d_in[0];  // [B,L,H]
    const float* efhs = (const float*)d_in[1];  // [B,H]
    const float* zseq = (const float*)d_in[2];  // [B,L,Z]
    const int*   mask = (const int*)d_in[3];    // [B,L]
    const float* Wq   = (const float*)d_in[4];  // [H,H]
    const float* Wk   = (const float*)d_in[5];  // [H,H]
    const float* Wv   = (const float*)d_in[6];  // [Z,Z]
    float* out  = (float*)d_out;
    float* attn = out + (size_t)BB * LL * ZZ;

    float* ws   = (float*)d_ws;
    float* zsum = ws;             //  8192 floats  (zeroed)
    float* kbuf = ws + 8192;      // 16384 floats  (zeroed)
    float* Vs   = ws + 24576;     //  8192 floats  (zeroed)
    float* sbuf = ws + 32768;     // 32768 floats
    float* wbuf = ws + 65536;     // 32768 floats
    float* kq   = ws + 98304;     // 16384 floats

    hipMemsetAsync(ws, 0, 32768 * sizeof(float), stream);  // zsum+kbuf+Vs
    kA<<<  640, 256, 0, stream>>>(efhs, Wk, zseq, kbuf, zsum);
    kB<<< 4224, 256, 0, stream>>>(Wq, kbuf, zsum, Wv, kq, Vs);
    kC<<< 8192, 256, 0, stream>>>(erhs, kq, mask, sbuf);
    kD<<<   16, 256, 0, stream>>>(sbuf, wbuf);
    kE<<< 4096, 256, 0, stream>>>(wbuf, Vs, out, attn);
}

// Round 6
// 502.061 us; speedup vs baseline: 1.9413x; 1.0054x over previous
//
#include <hip/hip_runtime.h>

#define BB 16
#define LL 2048
#define HH 1024
#define ZZ 512
#define NEGV -1e9f

typedef float v4f __attribute__((ext_vector_type(4)));

__device__ __forceinline__ float dot4(float4 a, float4 b) {
    return a.x * b.x + a.y * b.y + a.z * b.z + a.w * b.w;
}

// Dispatch A: blocks [0,128): kbuf[b,hp] += sum over 128-h segment of efhs[b,h]*Wk[h,hp]
//             blocks [128,640): zsum[b,z0] += 64-row chunk of zseq[b,:,z0]
__global__ __launch_bounds__(256) void kA(const float* __restrict__ efhs,
                                          const float* __restrict__ Wk,
                                          const float* __restrict__ zseq,
                                          float* __restrict__ kbuf,
                                          float* __restrict__ zsum) {
    int t = threadIdx.x;
    if (blockIdx.x < 128) {
        int b = blockIdx.x >> 3, hseg = blockIdx.x & 7;   // h in [hseg*128, +128)
        const float* e  = efhs + b * HH + hseg * 128;
        const float* wk = Wk + (size_t)(hseg * 128) * HH;
        float a0 = 0.f, a1 = 0.f, a2 = 0.f, a3 = 0.f;
        for (int h = 0; h < 128; ++h) {
            float ev = e[h];
            const float* wr = wk + (size_t)h * HH;
            a0 += ev * wr[t];
            a1 += ev * wr[t + 256];
            a2 += ev * wr[t + 512];
            a3 += ev * wr[t + 768];
        }
        atomicAdd(&kbuf[b * HH + t],       a0);
        atomicAdd(&kbuf[b * HH + t + 256], a1);
        atomicAdd(&kbuf[b * HH + t + 512], a2);
        atomicAdd(&kbuf[b * HH + t + 768], a3);
    } else {
        int blk = blockIdx.x - 128;                        // b(16) x jc(32)
        int b = blk >> 5, jc = blk & 31;
        const float* p = zseq + ((size_t)(b * LL + jc * 64)) * ZZ;
        float a0 = 0.f, a1 = 0.f;
        for (int j = 0; j < 64; ++j) {
            const float* pj = p + (size_t)j * ZZ;
            a0 += pj[t];
            a1 += pj[t + 256];
        }
        atomicAdd(&zsum[b * ZZ + t],       a0);
        atomicAdd(&zsum[b * ZZ + t + 256], a1);
    }
}

// Dispatch B: blocks [0,4096): kq[b,h] = Wq[h,:].kbuf[b,:]  (wave per (h,b) pair)
//             blocks [4096,4224): Vs[b,z] += (z0-chunk) zsum[b,z0]*Wv[z0,z]
__global__ __launch_bounds__(256) void kB(const float* __restrict__ Wq,
                                          const float* __restrict__ kbuf,
                                          const float* __restrict__ zsum,
                                          const float* __restrict__ Wv,
                                          float* __restrict__ kq,
                                          float* __restrict__ Vs) {
    int t = threadIdx.x;
    int wid = t >> 6, lane = t & 63;
    if (blockIdx.x < 4096) {
        int h = blockIdx.x >> 2;
        int b = ((blockIdx.x & 3) << 2) + wid;
        const float4* wrow = (const float4*)(Wq + (size_t)h * HH);
        const float4* kb   = (const float4*)(kbuf + b * HH);
        float acc = dot4(wrow[lane], kb[lane])
                  + dot4(wrow[64 + lane], kb[64 + lane])
                  + dot4(wrow[128 + lane], kb[128 + lane])
                  + dot4(wrow[192 + lane], kb[192 + lane]);
        for (int off = 32; off > 0; off >>= 1) acc += __shfl_down(acc, off);
        if (lane == 0) kq[b * HH + h] = acc;
    } else {
        int blk = blockIdx.x - 4096;                       // b(16) x z0c(8)
        int b = blk >> 3, z0c = blk & 7;
        const float* zs = zsum + b * ZZ + z0c * 64;
        const float* wv = Wv + (size_t)(z0c * 64) * ZZ;
        float a0 = 0.f, a1 = 0.f;
        for (int z0 = 0; z0 < 64; ++z0) {
            float zv = zs[z0];
            const float* wr = wv + (size_t)z0 * ZZ;
            a0 += zv * wr[t];
            a1 += zv * wr[t + 256];
        }
        atomicAdd(&Vs[b * ZZ + t],       a0);
        atomicAdd(&Vs[b * ZZ + t + 256], a1);
    }
}

// Dispatch C: s[b,i] = (erhs[b,i].kq[b])/32, masked  (wave per row; pure erhs stream)
__global__ __launch_bounds__(256) void kC(const float* __restrict__ erhs,
                                          const float* __restrict__ kq,
                                          const int* __restrict__ mask,
                                          float* __restrict__ sbuf) {
    int row = blockIdx.x * 4 + (threadIdx.x >> 6);  // b*L + i
    int lane = threadIdx.x & 63;
    int b = row >> 11;
    const float4* e  = (const float4*)(erhs + (size_t)row * HH);
    const float4* kb = (const float4*)(kq + b * HH);
    float acc = dot4(e[lane], kb[lane])
              + dot4(e[64 + lane], kb[64 + lane])
              + dot4(e[128 + lane], kb[128 + lane])
              + dot4(e[192 + lane], kb[192 + lane]);
    for (int off = 32; off > 0; off >>= 1) acc += __shfl_down(acc, off);
    if (lane == 0) {
        float v = acc * (1.0f / 32.0f);
        if (mask[row] == 0) v = NEGV;
        sbuf[row] = v;
    }
}

// Dispatch E (fused softmax + epilogue): 8 rows per block (4096 blocks).
// Each block recomputes its b's softmax max/sum from sbuf (L2-hot, deterministic
// and bit-identical across blocks of the same b), then:
//   out[b,i,:]  = w[b,i]*Vs[b,:]   attn[b,i,:] = w[b,i]   (nontemporal stores)
__global__ __launch_bounds__(256) void kE(const float* __restrict__ sbuf,
                                          const float* __restrict__ Vs,
                                          float* __restrict__ out,
                                          float* __restrict__ attn) {
    __shared__ float red[8];
    __shared__ float wsh[8];
    int row0 = blockIdx.x * 8;      // all 8 rows share b (256 blocks per b)
    int b = row0 >> 11;
    int i0 = row0 & (LL - 1);
    int t = threadIdx.x;
    int wid = t >> 6, lane = t & 63;
    const float* sb = sbuf + b * LL;

    // max over i
    float m = -3.4e38f;
#pragma unroll
    for (int i = 0; i < 8; ++i) m = fmaxf(m, sb[t + i * 256]);
    for (int off = 32; off > 0; off >>= 1) m = fmaxf(m, __shfl_down(m, off));
    if (lane == 0) red[wid] = m;
    __syncthreads();
    m = fmaxf(fmaxf(red[0], red[1]), fmaxf(red[2], red[3]));

    // sum of exp
    float ssum = 0.f;
#pragma unroll
    for (int i = 0; i < 8; ++i) ssum += __expf(sb[t + i * 256] - m);
    for (int off = 32; off > 0; off >>= 1) ssum += __shfl_down(ssum, off);
    if (lane == 0) red[4 + wid] = ssum;
    __syncthreads();
    float inv = 1.0f / (red[4] + red[5] + red[6] + red[7]);

    // this block's 8 row-weights
    if (t < 8) wsh[t] = __expf(sb[i0 + t] - m) * inv;
    __syncthreads();

    // out: 1024 float4 per block, 4 per thread; col = t&127 is k-invariant
    {
        float4 v = ((const float4*)(Vs + b * ZZ))[t & 127];
        int r0 = t >> 7;            // 0 or 1
#pragma unroll
        for (int k = 0; k < 4; ++k) {
            int r = r0 + 2 * k;
            float wv = wsh[r];
            v4f ov = {wv * v.x, wv * v.y, wv * v.z, wv * v.w};
            __builtin_nontemporal_store(
                ov, (v4f*)(out + (size_t)(row0 + r) * ZZ) + (t & 127));
        }
    }

    // attn: 8 rows x 512 float4
#pragma unroll
    for (int r = 0; r < 8; ++r) {
        float wv = wsh[r];
        v4f pk = {wv, wv, wv, wv};
        v4f* p = (v4f*)(attn + (size_t)(row0 + r) * LL);
        __builtin_nontemporal_store(pk, p + t);
        __builtin_nontemporal_store(pk, p + t + 256);
    }
}

extern "C" void kernel_launch(void* const* d_in, const int* in_sizes, int n_in,
                              void* d_out, int out_size, void* d_ws, size_t ws_size,
                              hipStream_t stream) {
    const float* erhs = (const float*)d_in[0];  // [B,L,H]
    const float* efhs = (const float*)d_in[1];  // [B,H]
    const float* zseq = (const float*)d_in[2];  // [B,L,Z]
    const int*   mask = (const int*)d_in[3];    // [B,L]
    const float* Wq   = (const float*)d_in[4];  // [H,H]
    const float* Wk   = (const float*)d_in[5];  // [H,H]
    const float* Wv   = (const float*)d_in[6];  // [Z,Z]
    float* out  = (float*)d_out;
    float* attn = out + (size_t)BB * LL * ZZ;

    float* ws   = (float*)d_ws;
    float* zsum = ws;             //  8192 floats  (zeroed)
    float* kbuf = ws + 8192;      // 16384 floats  (zeroed)
    float* Vs   = ws + 24576;     //  8192 floats  (zeroed)
    float* sbuf = ws + 32768;     // 32768 floats
    float* kq   = ws + 65536;     // 16384 floats

    hipMemsetAsync(ws, 0, 32768 * sizeof(float), stream);  // zsum+kbuf+Vs
    kA<<<  640, 256, 0, stream>>>(efhs, Wk, zseq, kbuf, zsum);
    kB<<< 4224, 256, 0, stream>>>(Wq, kbuf, zsum, Wv, kq, Vs);
    kC<<< 8192, 256, 0, stream>>>(erhs, kq, mask, sbuf);
    kE<<< 4096, 256, 0, stream>>>(sbuf, Vs, out, attn);
}